// Round 12
// baseline (502.119 us; speedup 1.0000x reference)
//
#include <hip/hip_runtime.h>
#include <math.h>

#define DD 64
#define EDA 16

// packed B-fragment offsets (units of 64-lane short8 entries)
#define FR_E1 0
#define FR_E2 4
#define FR_N1 12
#define FR_N2 20
#define FR_O1 28
#define FR_O2 44
#define FR_TOT 52

#define PADH 72   // hid bf16 LDS row stride (ushort) for node/out kernels
#define PADF 68   // f32 LDS row stride (float)

// edge kernel strides
#define HS 72     // unified tile row stride in ushort (144B; %16==0 for b128)

typedef unsigned int u32;
typedef unsigned long long u64;
typedef __attribute__((ext_vector_type(8))) short short8;
typedef __attribute__((ext_vector_type(4))) float f32x4;

static __device__ __forceinline__ float silu(float v) {
    return v / (1.0f + __expf(-v));
}
static __device__ __forceinline__ unsigned short f2bf(float f) {
    unsigned u = __float_as_uint(f);
    unsigned r = u + 0x7FFFu + ((u >> 16) & 1u);   // RNE
    return (unsigned short)(r >> 16);
}
static __device__ __forceinline__ float bf2f(unsigned short u) {
    return __uint_as_float(((unsigned)u) << 16);
}
static __device__ __forceinline__ float bflo(u32 v) {
    return __uint_as_float(v << 16);
}
static __device__ __forceinline__ float bfhi(u32 v) {
    return __uint_as_float(v & 0xFFFF0000u);
}
static __device__ __forceinline__ unsigned cvt_pk_bf16(float lo, float hi) {
    unsigned r;
    asm("v_cvt_pk_bf16_f32 %0, %1, %2" : "=v"(r) : "v"(lo), "v"(hi));
    return r;
}
static __device__ __forceinline__ int bperm(int idx_lane, int v) {
    return __builtin_amdgcn_ds_bpermute(idx_lane << 2, v);
}
// LDS write->read fence within a wave (rule #18: sched_barrier after lgkmcnt)
static __device__ __forceinline__ void wave_lds_fence() {
    asm volatile("s_waitcnt lgkmcnt(0)" ::: "memory");
    __builtin_amdgcn_sched_barrier(0);
}

// ---------------- weight pre-pack into MFMA B-fragment layout ----------------
__global__ __launch_bounds__(256) void k_pack_w(
    const float* __restrict__ eW1, const float* __restrict__ eW2,
    const float* __restrict__ nW1, const float* __restrict__ nW2,
    const float* __restrict__ oW1, const float* __restrict__ oW2,
    unsigned short* __restrict__ wpk)
{
    int t = threadIdx.x;
    int nt = t >> 6, l = t & 63;
    int kc = l >> 4, n0 = l & 15;

    #pragma unroll
    for (int j = 0; j < 8; ++j) {
        int k = kc*8 + j;
        int orig = (k < 16) ? (9 + k) : ((k < 25) ? (k - 16) : -1);
        float v = (orig >= 0) ? eW1[orig*DD + nt*16 + n0] : 0.0f;
        wpk[((size_t)((FR_E1 + nt)*64 + l))*8 + j] = f2bf(v);
    }
    #pragma unroll
    for (int s = 0; s < 2; ++s) {
        #pragma unroll
        for (int j = 0; j < 8; ++j) {
            int k = s*32 + kc*8 + j;
            wpk[((size_t)((FR_E2 + s*4 + nt)*64 + l))*8 + j] = f2bf(eW2[k*DD + nt*16 + n0]);
            wpk[((size_t)((FR_N1 + s*4 + nt)*64 + l))*8 + j] = f2bf(nW1[k*DD + nt*16 + n0]);
            wpk[((size_t)((FR_N2 + s*4 + nt)*64 + l))*8 + j] = f2bf(nW2[k*DD + nt*16 + n0]);
            wpk[((size_t)((FR_O2 + s*4 + nt)*64 + l))*8 + j] = f2bf(oW2[k*DD + nt*16 + n0]);
        }
    }
    #pragma unroll
    for (int s = 0; s < 4; ++s) {
        #pragma unroll
        for (int j = 0; j < 8; ++j) {
            int k = s*32 + kc*8 + j;
            wpk[((size_t)((FR_O1 + s*4 + nt)*64 + l))*8 + j] = f2bf(oW1[k*DD + nt*16 + n0]);
        }
    }
}

// ---------------- fused: node MLP (blocks < nb) + histogram (blocks >= nb) --
__global__ __launch_bounds__(256, 2) void k_node_hist(
    const float* __restrict__ x,
    const unsigned short* __restrict__ wpk,
    const float* __restrict__ b1, const float* __restrict__ b2,
    unsigned short* __restrict__ x_tb, int n, int nodeBlocks,
    const int* __restrict__ col, u32* __restrict__ cnt, int n_e)
{
    __shared__ __align__(16) unsigned short tile[4][16*PADH];
    const int tid  = threadIdx.x;

    if (blockIdx.x >= nodeBlocks) {
        int g = (blockIdx.x - nodeBlocks) * 256 + tid;
        int base = g * 4;
        if (base + 3 < n_e) {
            int4 c = ((const int4*)col)[g];
            atomicAdd(&cnt[c.x], 1u);
            atomicAdd(&cnt[c.y], 1u);
            atomicAdd(&cnt[c.z], 1u);
            atomicAdd(&cnt[c.w], 1u);
        } else {
            for (int e = base; e < n_e; ++e) atomicAdd(&cnt[col[e]], 1u);
        }
        return;
    }

    const int wv   = tid >> 6;
    const int lane = tid & 63;
    const int kc   = lane >> 4;
    const int n0   = lane & 15;
    const int rbase = kc * 4;

    const short8* fb = (const short8*)wpk;
    short8 bw1[2][4], bw2[2][4];
    #pragma unroll
    for (int s = 0; s < 2; ++s)
        #pragma unroll
        for (int nt = 0; nt < 4; ++nt) {
            bw1[s][nt] = fb[(FR_N1 + s*4 + nt)*64 + lane];
            bw2[s][nt] = fb[(FR_N2 + s*4 + nt)*64 + lane];
        }
    float b1v[4], b2v[4];
    #pragma unroll
    for (int nt = 0; nt < 4; ++nt) { b1v[nt] = b1[nt*16 + n0]; b2v[nt] = b2[nt*16 + n0]; }

    const int base = blockIdx.x*64 + wv*16;
    int rc = min(base + n0, n - 1);
    const float* xr = x + (size_t)rc * DD;

    short8 a[2];
    #pragma unroll
    for (int m = 0; m < 2; ++m) {
        float4 u0 = *(const float4*)(xr + m*32 + kc*8);
        float4 u1 = *(const float4*)(xr + m*32 + kc*8 + 4);
        unsigned* au = (unsigned*)&a[m];
        au[0] = cvt_pk_bf16(u0.x, u0.y);
        au[1] = cvt_pk_bf16(u0.z, u0.w);
        au[2] = cvt_pk_bf16(u1.x, u1.y);
        au[3] = cvt_pk_bf16(u1.z, u1.w);
    }

    f32x4 zz = {0.f, 0.f, 0.f, 0.f};
    f32x4 hacc[4] = {zz, zz, zz, zz};
    #pragma unroll
    for (int m = 0; m < 2; ++m)
        #pragma unroll
        for (int nt = 0; nt < 4; ++nt)
            hacc[nt] = __builtin_amdgcn_mfma_f32_16x16x32_bf16(a[m], bw1[m][nt], hacc[nt], 0, 0, 0);

    #pragma unroll
    for (int nt = 0; nt < 4; ++nt)
        #pragma unroll
        for (int r = 0; r < 4; ++r)
            tile[wv][(rbase + r)*PADH + nt*16 + n0] = f2bf(silu(hacc[nt][r] + b1v[nt]));
    __syncthreads();

    short8 a2_0 = *(const short8*)&tile[wv][n0*PADH +  0 + kc*8];
    short8 a2_1 = *(const short8*)&tile[wv][n0*PADH + 32 + kc*8];
    f32x4 oacc[4];
    #pragma unroll
    for (int nt = 0; nt < 4; ++nt) {
        oacc[nt] = __builtin_amdgcn_mfma_f32_16x16x32_bf16(a2_0, bw2[0][nt], zz, 0, 0, 0);
        oacc[nt] = __builtin_amdgcn_mfma_f32_16x16x32_bf16(a2_1, bw2[1][nt], oacc[nt], 0, 0, 0);
    }
    __syncthreads();

    #pragma unroll
    for (int nt = 0; nt < 4; ++nt)
        #pragma unroll
        for (int r = 0; r < 4; ++r)
            tile[wv][(rbase + r)*PADH + nt*16 + n0] = f2bf(oacc[nt][r] + b2v[nt]);
    __syncthreads();

    int ei = lane >> 2, q = lane & 3;
    int er = base + ei;
    if (er < n) {
        uint4* dst = (uint4*)(x_tb + (size_t)er * DD);
        dst[q]     = *(const uint4*)&tile[wv][ei*PADH + q*8];
        dst[q + 4] = *(const uint4*)&tile[wv][ei*PADH + (q + 4)*8];
    }
}

// ---------------- scans ----------------
__global__ __launch_bounds__(256) void k_scan1(
    const u32* __restrict__ cnt, u32* __restrict__ bsum, int n)
{
    __shared__ u32 s[256];
    int i = blockIdx.x * 256 + threadIdx.x;
    s[threadIdx.x] = (i < n) ? cnt[i] : 0u;
    __syncthreads();
    for (int o = 128; o > 0; o >>= 1) {
        if (threadIdx.x < o) s[threadIdx.x] += s[threadIdx.x + o];
        __syncthreads();
    }
    if (threadIdx.x == 0) bsum[blockIdx.x] = s[0];
}

__global__ __launch_bounds__(512) void k_scan2(
    const u32* __restrict__ bsum, u32* __restrict__ boff, int nb)
{
    __shared__ u32 s[512];
    int t = threadIdx.x;
    u32 v = (t < nb) ? bsum[t] : 0u;
    s[t] = v;
    __syncthreads();
    for (int o = 1; o < 512; o <<= 1) {
        u32 a = (t >= o) ? s[t - o] : 0u;
        __syncthreads();
        s[t] += a;
        __syncthreads();
    }
    if (t < nb) boff[t] = s[t] - v;
}

__global__ __launch_bounds__(256) void k_scan3(
    const u32* __restrict__ cnt, const u32* __restrict__ boff,
    u32* __restrict__ wp, int n)
{
    __shared__ u32 s[256];
    int t = threadIdx.x;
    int i = blockIdx.x * 256 + t;
    u32 v = (i < n) ? cnt[i] : 0u;
    s[t] = v;
    __syncthreads();
    for (int o = 1; o < 256; o <<= 1) {
        u32 a = (t >= o) ? s[t - o] : 0u;
        __syncthreads();
        s[t] += a;
        __syncthreads();
    }
    if (i < n) wp[i] = boff[blockIdx.x] + s[t] - v;
}

// ---------------- counting-sort scatter + agg zero ----------------
__global__ __launch_bounds__(256) void k_scatter(
    const int* __restrict__ row, const int* __restrict__ col,
    u32* __restrict__ wp, u64* __restrict__ ce,
    float* __restrict__ agg, int n_agg4, int n_e)
{
    int e = blockIdx.x * 256 + threadIdx.x;
    if (e < n_agg4) {
        float4 z = {0.f, 0.f, 0.f, 0.f};
        ((float4*)agg)[e] = z;
    }
    if (e >= n_e) return;
    int c = col[e];
    int r = row[e];
    u32 p = atomicAdd(&wp[c], 1u);
    u32 lo = (u32)e | ((u32)r << 21);
    u32 hi = ((u32)r >> 11) | ((u32)c << 6);
    u64 pk = (u64)lo | ((u64)hi << 32);
    __builtin_nontemporal_store(pk, &ce[p]);
}

// ---------------- fused edge kernel: swapped GEMMs, overlaid LDS tile -------
// 256 threads = 4 waves; wave owns 64 sorted slots, 4 sub-tiles of 16 edges.
// LDS: one 16x72 bf16 tile per wave (hid then msg overlay) + 8KB shared bw2.
__global__ __launch_bounds__(256, 8) void k_edge_fused(
    const float* __restrict__ pos,
    const float* __restrict__ edge_attr,
    const u64* __restrict__ ce,
    const unsigned short* __restrict__ x_tb,
    const unsigned short* __restrict__ wpk,
    const float* __restrict__ b1, const float* __restrict__ b2,
    float* __restrict__ agg, int n_e)
{
    __shared__ __align__(16) unsigned short t_s[4][16*HS];   // 9216 B (hid/msg overlay)
    __shared__ __align__(16) unsigned short wls[8*64*8];     // 8192 B (edge W2 frags)

    const int tid  = threadIdx.x;
    const int wv   = tid >> 6;
    const int lane = tid & 63;
    const int kc   = lane >> 4;
    const int n0   = lane & 15;

    // stage bw2 into block-shared LDS (contiguous 8KB at wpk + FR_E2*512 shorts)
    {
        const uint4* wsrc = (const uint4*)(wpk + FR_E2*64*8);
        uint4* wdst = (uint4*)wls;
        wdst[tid*2]     = wsrc[tid*2];
        wdst[tid*2 + 1] = wsrc[tid*2 + 1];
    }

    const short8* fb = (const short8*)wpk;
    short8 bw1[4];
    #pragma unroll
    for (int nt = 0; nt < 4; ++nt) bw1[nt] = fb[(FR_E1 + nt)*64 + lane];

    // biases packed bf16: lane holds features f = nt*16 + kc*4 + r
    uint2 bp1[4], bp2[4];
    #pragma unroll
    for (int nt = 0; nt < 4; ++nt) {
        float4 q1 = *(const float4*)(b1 + nt*16 + kc*4);
        float4 q2 = *(const float4*)(b2 + nt*16 + kc*4);
        bp1[nt].x = cvt_pk_bf16(q1.x, q1.y); bp1[nt].y = cvt_pk_bf16(q1.z, q1.w);
        bp2[nt].x = cvt_pk_bf16(q2.x, q2.y); bp2[nt].y = cvt_pk_bf16(q2.z, q2.w);
    }

    const int gbase = blockIdx.x*256 + wv*64;
    int g  = gbase + lane;
    int gc = min(g, n_e - 1);
    u64 pk = ce[gc];
    u32 pklo = (u32)pk, pkhi = (u32)(pk >> 32);
    int eo = (int)(pklo & 0x1FFFFFu);
    int rw = (int)((pklo >> 21) | ((pkhi & 0x3Fu) << 11));
    int cl = (int)(pkhi >> 6);

    // ---- geometry + SH: once per edge (this lane), packed to bf16 regs ----
    float ax = pos[3*rw+0] - pos[3*cl+0];
    float ay = pos[3*rw+1] - pos[3*cl+1];
    float az = pos[3*rw+2] - pos[3*cl+2];
    float len = sqrtf(fmaf(ax,ax, fmaf(ay,ay, az*az)) + 1e-12f);
    float dx = ax/len, dy = ay/len, dz = az/len;
    float n2 = sqrtf(fmaf(dx,dx, fmaf(dy,dy, dz*dz)));
    float inv = 1.0f/(n2 + 1e-10f);
    dx *= inv; dy *= inv; dz *= inv;

    u32 shp01 = cvt_pk_bf16(0.28209479177387814f, 0.4886025119029199f*dy);
    u32 shp23 = cvt_pk_bf16(0.4886025119029199f*dz, 0.4886025119029199f*dx);
    u32 shp45 = cvt_pk_bf16(1.0925484305920792f*dx*dy, 1.0925484305920792f*dy*dz);
    u32 shp67 = cvt_pk_bf16(0.31539156525252005f*(3.0f*dz*dz - 1.0f),
                            1.0925484305920792f*dx*dz);
    u32 shp8  = cvt_pk_bf16(0.5462742152960396f*(dx*dx - dy*dy), 0.0f);

    // ---- wave-uniform flush mask ----
    int cln = bperm(min(lane + 1, 63), cl);
    u64 fmask = __ballot(cln != cl) | 0x8000800080008000ull;

    f32x4 zz = {0.f, 0.f, 0.f, 0.f};

    __syncthreads();   // wls staged (once per block)

    #pragma unroll 1
    for (int tt = 0; tt < 4; ++tt) {
        const int le = tt*16 + n0;
        bool valid = (gbase + le) < n_e;

        // cross-lane broadcasts + global gathers
        int ea  = bperm(le, eo);
        int rv  = bperm(le, rw);
        u32 s01 = (u32)bperm(le, (int)shp01);
        u32 s23 = (u32)bperm(le, (int)shp23);
        u32 s45 = (u32)bperm(le, (int)shp45);
        u32 s67 = (u32)bperm(le, (int)shp67);
        u32 s8  = (u32)bperm(le, (int)shp8);

        const unsigned short* xrow = x_tb + (size_t)rv * DD;
        uint2 xv0 = *(const uint2*)(xrow +  0 + kc*4);
        uint2 xv1 = *(const uint2*)(xrow + 16 + kc*4);
        uint2 xv2 = *(const uint2*)(xrow + 32 + kc*4);
        uint2 xv3 = *(const uint2*)(xrow + 48 + kc*4);

        // feature B-frag: lane holds F[e = le][k = kc*8 + j]
        short8 af;
        unsigned* au = (unsigned*)&af;
        if (kc < 2) {
            const float4* ap = (const float4*)(edge_attr + (size_t)ea*EDA + kc*8);
            float4 a0 = ap[0], a1 = ap[1];
            au[0] = cvt_pk_bf16(a0.x, a0.y);
            au[1] = cvt_pk_bf16(a0.z, a0.w);
            au[2] = cvt_pk_bf16(a1.x, a1.y);
            au[3] = cvt_pk_bf16(a1.z, a1.w);
        } else if (kc == 2) {
            au[0] = s01; au[1] = s23; au[2] = s45; au[3] = s67;
        } else {
            au[0] = s8; au[1] = 0u; au[2] = 0u; au[3] = 0u;
        }

        // GEMM1 swapped: lane gets hid[e=n0][f=nt*16+kc*4+r]
        f32x4 hacc[4];
        #pragma unroll
        for (int nt = 0; nt < 4; ++nt)
            hacc[nt] = __builtin_amdgcn_mfma_f32_16x16x32_bf16(bw1[nt], af, zz, 0, 0, 0);

        #pragma unroll
        for (int nt = 0; nt < 4; ++nt) {
            float h0 = silu(hacc[nt][0] + bflo(bp1[nt].x));
            float h1 = silu(hacc[nt][1] + bfhi(bp1[nt].x));
            float h2 = silu(hacc[nt][2] + bflo(bp1[nt].y));
            float h3 = silu(hacc[nt][3] + bfhi(bp1[nt].y));
            uint2 pr;
            pr.x = cvt_pk_bf16(h0, h1);
            pr.y = cvt_pk_bf16(h2, h3);
            *(uint2*)&t_s[wv][n0*HS + nt*16 + kc*4] = pr;
        }
        wave_lds_fence();

        // GEMM2 swapped: W2 fragments from block-shared LDS
        short8 bf0 = *(const short8*)&t_s[wv][n0*HS +  0 + kc*8];
        short8 bf1 = *(const short8*)&t_s[wv][n0*HS + 32 + kc*8];
        f32x4 oacc[4];
        #pragma unroll
        for (int nt = 0; nt < 4; ++nt) {
            short8 w0 = *(const short8*)&wls[((0*4 + nt)*64 + lane)*8];
            oacc[nt] = __builtin_amdgcn_mfma_f32_16x16x32_bf16(w0, bf0, zz, 0, 0, 0);
            short8 w1 = *(const short8*)&wls[((1*4 + nt)*64 + lane)*8];
            oacc[nt] = __builtin_amdgcn_mfma_f32_16x16x32_bf16(w1, bf1, oacc[nt], 0, 0, 0);
        }

        // epilogue: msg (bf16, overlaid on t_s) = (out + b2) * x_t[row]; zero invalid
        if (!valid) {
            xv0.x = xv0.y = xv1.x = xv1.y = 0u;
            xv2.x = xv2.y = xv3.x = xv3.y = 0u;
        }
        {
            float m0, m1, m2, m3;
            uint2 pr;
            m0 = (oacc[0][0] + bflo(bp2[0].x)) * bflo(xv0.x);
            m1 = (oacc[0][1] + bfhi(bp2[0].x)) * bfhi(xv0.x);
            m2 = (oacc[0][2] + bflo(bp2[0].y)) * bflo(xv0.y);
            m3 = (oacc[0][3] + bfhi(bp2[0].y)) * bfhi(xv0.y);
            pr.x = cvt_pk_bf16(m0, m1); pr.y = cvt_pk_bf16(m2, m3);
            *(uint2*)&t_s[wv][n0*HS +  0 + kc*4] = pr;
            m0 = (oacc[1][0] + bflo(bp2[1].x)) * bflo(xv1.x);
            m1 = (oacc[1][1] + bfhi(bp2[1].x)) * bfhi(xv1.x);
            m2 = (oacc[1][2] + bflo(bp2[1].y)) * bflo(xv1.y);
            m3 = (oacc[1][3] + bfhi(bp2[1].y)) * bfhi(xv1.y);
            pr.x = cvt_pk_bf16(m0, m1); pr.y = cvt_pk_bf16(m2, m3);
            *(uint2*)&t_s[wv][n0*HS + 16 + kc*4] = pr;
            m0 = (oacc[2][0] + bflo(bp2[2].x)) * bflo(xv2.x);
            m1 = (oacc[2][1] + bfhi(bp2[2].x)) * bfhi(xv2.x);
            m2 = (oacc[2][2] + bflo(bp2[2].y)) * bflo(xv2.y);
            m3 = (oacc[2][3] + bfhi(bp2[2].y)) * bfhi(xv2.y);
            pr.x = cvt_pk_bf16(m0, m1); pr.y = cvt_pk_bf16(m2, m3);
            *(uint2*)&t_s[wv][n0*HS + 32 + kc*4] = pr;
            m0 = (oacc[3][0] + bflo(bp2[3].x)) * bflo(xv3.x);
            m1 = (oacc[3][1] + bfhi(bp2[3].x)) * bfhi(xv3.x);
            m2 = (oacc[3][2] + bflo(bp2[3].y)) * bflo(xv3.y);
            m3 = (oacc[3][3] + bfhi(bp2[3].y)) * bfhi(xv3.y);
            pr.x = cvt_pk_bf16(m0, m1); pr.y = cvt_pk_bf16(m2, m3);
            *(uint2*)&t_s[wv][n0*HS + 48 + kc*4] = pr;
        }
        wave_lds_fence();

        // segmented reduce: lane = feature; scalar flush test via fmask
        {
            float acc = 0.0f;
            #pragma unroll
            for (int r = 0; r < 16; ++r) {
                acc += bf2f(t_s[wv][r*HS + lane]);
                if ((fmask >> (tt*16 + r)) & 1ull) {     // wave-uniform branch
                    int cur = __builtin_amdgcn_readlane(cl, tt*16 + r);
                    unsafeAtomicAdd(&agg[(size_t)cur*DD + lane], acc);
                    acc = 0.0f;
                }
            }
        }
    }
}

// ---------------- MFMA out MLP (+ /cnt) + fused BN partial sums ----------------
__global__ __launch_bounds__(256, 2) void k_out_mfma(
    const float* __restrict__ agg, const u32* __restrict__ cnt,
    const float* __restrict__ x,
    const unsigned short* __restrict__ wpk,
    const float* __restrict__ b1, const float* __restrict__ b2,
    float* __restrict__ h, float* __restrict__ sums, int n)
{
    __shared__ __align__(16) unsigned short htile[4][16*PADH];
    __shared__ __align__(16) float otile[4][16*PADF];
    const int tid  = threadIdx.x;
    const int wv   = tid >> 6;
    const int lane = tid & 63;
    const int kc   = lane >> 4;
    const int n0   = lane & 15;
    const int rbase = kc * 4;

    const short8* fb = (const short8*)wpk;
    short8 bw1[4][4], bw2[2][4];
    #pragma unroll
    for (int s = 0; s < 4; ++s)
        #pragma unroll
        for (int nt = 0; nt < 4; ++nt) bw1[s][nt] = fb[(FR_O1 + s*4 + nt)*64 + lane];
    #pragma unroll
    for (int s = 0; s < 2; ++s)
        #pragma unroll
        for (int nt = 0; nt < 4; ++nt) bw2[s][nt] = fb[(FR_O2 + s*4 + nt)*64 + lane];

    float b1v[4], b2v[4];
    #pragma unroll
    for (int nt = 0; nt < 4; ++nt) { b1v[nt] = b1[nt*16 + n0]; b2v[nt] = b2[nt*16 + n0]; }

    const int base = blockIdx.x*64 + wv*16;
    int rc = min(base + n0, n - 1);
    const float* ar = agg + (size_t)rc * DD;
    const float* xr = x   + (size_t)rc * DD;
    float invc = 1.0f / fmaxf((float)cnt[rc], 1.0f);

    short8 a[4];
    #pragma unroll
    for (int m = 0; m < 4; ++m) {
        const float* src = (m < 2) ? (ar + m*32 + kc*8) : (xr + (m-2)*32 + kc*8);
        float4 u0 = *(const float4*)(src);
        float4 u1 = *(const float4*)(src + 4);
        if (m < 2) {
            u0.x*=invc; u0.y*=invc; u0.z*=invc; u0.w*=invc;
            u1.x*=invc; u1.y*=invc; u1.z*=invc; u1.w*=invc;
        }
        unsigned* au = (unsigned*)&a[m];
        au[0] = cvt_pk_bf16(u0.x, u0.y);
        au[1] = cvt_pk_bf16(u0.z, u0.w);
        au[2] = cvt_pk_bf16(u1.x, u1.y);
        au[3] = cvt_pk_bf16(u1.z, u1.w);
    }

    f32x4 zz = {0.f, 0.f, 0.f, 0.f};
    f32x4 hacc[4] = {zz, zz, zz, zz};
    #pragma unroll
    for (int m = 0; m < 4; ++m)
        #pragma unroll
        for (int nt = 0; nt < 4; ++nt)
            hacc[nt] = __builtin_amdgcn_mfma_f32_16x16x32_bf16(a[m], bw1[m][nt], hacc[nt], 0, 0, 0);

    #pragma unroll
    for (int nt = 0; nt < 4; ++nt)
        #pragma unroll
        for (int r = 0; r < 4; ++r)
            htile[wv][(rbase + r)*PADH + nt*16 + n0] = f2bf(silu(hacc[nt][r] + b1v[nt]));
    __syncthreads();

    short8 a2_0 = *(const short8*)&htile[wv][n0*PADH +  0 + kc*8];
    short8 a2_1 = *(const short8*)&htile[wv][n0*PADH + 32 + kc*8];
    f32x4 oacc[4];
    #pragma unroll
    for (int nt = 0; nt < 4; ++nt) {
        oacc[nt] = __builtin_amdgcn_mfma_f32_16x16x32_bf16(a2_0, bw2[0][nt], zz, 0, 0, 0);
        oacc[nt] = __builtin_amdgcn_mfma_f32_16x16x32_bf16(a2_1, bw2[1][nt], oacc[nt], 0, 0, 0);
    }

    #pragma unroll
    for (int nt = 0; nt < 4; ++nt)
        #pragma unroll
        for (int r = 0; r < 4; ++r)
            otile[wv][(rbase + r)*PADF + nt*16 + n0] = oacc[nt][r] + b2v[nt];
    __syncthreads();

    int ei = lane >> 2, q = lane & 3;
    int er = base + ei;
    if (er < n) {
        float4* dst = (float4*)(h + (size_t)er * DD);
        #pragma unroll
        for (int k = 0; k < 4; ++k)
            dst[q + 4*k] = *(const float4*)&otile[wv][ei*PADF + (q + 4*k)*4];
    }

    if (tid < 64) {
        int f = tid;
        float s = 0.f, qq = 0.f;
        #pragma unroll
        for (int w = 0; w < 4; ++w) {
            int base_w = blockIdx.x*64 + w*16;
            int nv = n - base_w;
            nv = nv < 0 ? 0 : (nv > 16 ? 16 : nv);
            for (int r = 0; r < nv; ++r) {
                float v = otile[w][r*PADF + f];
                s += v; qq = fmaf(v, v, qq);
            }
        }
        unsafeAtomicAdd(&sums[f], s);
        unsafeAtomicAdd(&sums[DD + f], qq);
    }
}

// ---------------- BN normalize (finalize fused in) ----------------
__global__ __launch_bounds__(256) void k_bn_norm(
    float* __restrict__ h, const float* __restrict__ sums,
    const float* __restrict__ gamma, const float* __restrict__ beta,
    float inv_n, int total4)
{
    int g = blockIdx.x*256 + threadIdx.x;
    if (g >= total4) return;
    int f0 = (g*4) & (DD-1);
    float4 v = ((const float4*)h)[g];
    float4 sm = *(const float4*)(sums + f0);
    float4 sq = *(const float4*)(sums + DD + f0);
    float4 gm = *(const float4*)(gamma + f0);
    float4 bt = *(const float4*)(beta + f0);
    float m0 = sm.x*inv_n, m1 = sm.y*inv_n, m2 = sm.z*inv_n, m3 = sm.w*inv_n;
    float s0 = gm.x * rsqrtf(sq.x*inv_n - m0*m0 + 1e-5f);
    float s1 = gm.y * rsqrtf(sq.y*inv_n - m1*m1 + 1e-5f);
    float s2 = gm.z * rsqrtf(sq.z*inv_n - m2*m2 + 1e-5f);
    float s3 = gm.w * rsqrtf(sq.w*inv_n - m3*m3 + 1e-5f);
    v.x = fmaf(v.x - m0, s0, bt.x);
    v.y = fmaf(v.y - m1, s1, bt.y);
    v.z = fmaf(v.z - m2, s2, bt.z);
    v.w = fmaf(v.w - m3, s3, bt.w);
    ((float4*)h)[g] = v;
}

static inline size_t al16(size_t v) { return (v + 15) & ~(size_t)15; }

extern "C" void kernel_launch(void* const* d_in, const int* in_sizes, int n_in,
                              void* d_out, int out_size, void* d_ws, size_t ws_size,
                              hipStream_t stream)
{
    const float* x         = (const float*)d_in[0];
    const float* pos       = (const float*)d_in[1];
    const float* edge_attr = (const float*)d_in[2];
    const int*   row       = (const int*)d_in[3];
    const int*   col       = (const int*)d_in[4];
    const float* nW1 = (const float*)d_in[5];
    const float* nb1 = (const float*)d_in[6];
    const float* nW2 = (const float*)d_in[7];
    const float* nb2 = (const float*)d_in[8];
    const float* eW1 = (const float*)d_in[9];
    const float* eb1 = (const float*)d_in[10];
    const float* eW2 = (const float*)d_in[11];
    const float* eb2 = (const float*)d_in[12];
    const float* oW1 = (const float*)d_in[13];
    const float* ob1 = (const float*)d_in[14];
    const float* oW2 = (const float*)d_in[15];
    const float* ob2 = (const float*)d_in[16];
    const float* gamma = (const float*)d_in[17];
    const float* beta  = (const float*)d_in[18];

    const int N = in_sizes[0] / DD;   // 100000  (< 2^17 for packing)
    const int E = in_sizes[3];        // 1600000 (< 2^21 for packing)
    const int NB = (N + 255) / 256;   // 391
    const int nodeBlocks = (N + 63) / 64;       // 1563
    const int histBlocks = (E/4 + 255) / 256;   // 1563

    float* hout = (float*)d_out;
    char* ws = (char*)d_ws;

    size_t o_xtb  = 0;
    size_t o_cnt  = o_xtb  + (size_t)N*DD*2;
    size_t o_sums = o_cnt  + (size_t)N*4;
    size_t o_agg  = o_sums + 128*4;
    size_t o_wp   = o_agg  + (size_t)N*DD*4;
    size_t o_bsum = o_wp   + (size_t)N*4;
    size_t o_boff = al16(o_bsum + (size_t)NB*4);
    size_t o_wpk  = al16(o_boff + (size_t)NB*4);
    size_t o_ce   = al16(o_wpk + (size_t)FR_TOT*64*8*2);
    size_t need   = o_ce + (size_t)E*8;

    if (ws_size < need) return;

    unsigned short* x_tb = (unsigned short*)(ws + o_xtb);
    u32*   cnt  = (u32*)(ws + o_cnt);
    float* sums = (float*)(ws + o_sums);
    float* agg  = (float*)(ws + o_agg);
    u32*   wp   = (u32*)(ws + o_wp);
    u32*   bsum = (u32*)(ws + o_bsum);
    u32*   boff = (u32*)(ws + o_boff);
    unsigned short* wpk = (unsigned short*)(ws + o_wpk);
    u64*   ce   = (u64*)(ws + o_ce);

    // zero cnt + sums only (agg zeroed inside k_scatter)
    hipMemsetAsync(cnt, 0, (size_t)N*4 + 128*4, stream);

    k_pack_w<<<1, 256, 0, stream>>>(eW1, eW2, nW1, nW2, oW1, oW2, wpk);
    k_node_hist<<<nodeBlocks + histBlocks, 256, 0, stream>>>(
        x, wpk, nb1, nb2, x_tb, N, nodeBlocks, col, cnt, E);
    k_scan1<<<NB, 256, 0, stream>>>(cnt, bsum, N);
    k_scan2<<<1, 512, 0, stream>>>(bsum, boff, NB);
    k_scan3<<<NB, 256, 0, stream>>>(cnt, boff, wp, N);
    k_scatter<<<(E + 255)/256, 256, 0, stream>>>(row, col, wp, ce, agg, N*DD/4, E);
    k_edge_fused<<<(E + 255)/256, 256, 0, stream>>>(pos, edge_attr, ce, x_tb,
                                                    wpk, eb1, eb2, agg, E);
    k_out_mfma<<<(N + 63)/64, 256, 0, stream>>>(agg, cnt, x, wpk, ob1, ob2, hout, sums, N);
    k_bn_norm<<<(N*DD/4 + 255)/256, 256, 0, stream>>>(hout, sums, gamma, beta,
                                                      1.0f/(float)N, N*DD/4);
}

// Round 13
// 337.754 us; speedup vs baseline: 1.4866x; 1.4866x over previous
//
#include <hip/hip_runtime.h>
#include <math.h>

#define DD 64
#define EDA 16

// packed B-fragment offsets (units of 64-lane short8 entries)
#define FR_E1 0
#define FR_E2 4
#define FR_N1 12
#define FR_N2 20
#define FR_O1 28
#define FR_O2 44
#define FR_TOT 52

#define PADH 72   // hid bf16 LDS row stride (ushort) for node/out kernels
#define PADF 68   // f32 LDS row stride (float)

// edge kernel strides
#define HS 72     // unified tile row stride in ushort (144B; %16==0 for b128)

typedef unsigned int u32;
typedef unsigned long long u64;
typedef __attribute__((ext_vector_type(8))) short short8;
typedef __attribute__((ext_vector_type(4))) float f32x4;

static __device__ __forceinline__ float silu(float v) {
    return v / (1.0f + __expf(-v));
}
static __device__ __forceinline__ unsigned short f2bf(float f) {
    unsigned u = __float_as_uint(f);
    unsigned r = u + 0x7FFFu + ((u >> 16) & 1u);   // RNE
    return (unsigned short)(r >> 16);
}
static __device__ __forceinline__ float bf2f(unsigned short u) {
    return __uint_as_float(((unsigned)u) << 16);
}
static __device__ __forceinline__ float bflo(u32 v) {
    return __uint_as_float(v << 16);
}
static __device__ __forceinline__ float bfhi(u32 v) {
    return __uint_as_float(v & 0xFFFF0000u);
}
static __device__ __forceinline__ unsigned cvt_pk_bf16(float lo, float hi) {
    unsigned r;
    asm("v_cvt_pk_bf16_f32 %0, %1, %2" : "=v"(r) : "v"(lo), "v"(hi));
    return r;
}
static __device__ __forceinline__ int bperm(int idx_lane, int v) {
    return __builtin_amdgcn_ds_bpermute(idx_lane << 2, v);
}
// LDS write->read fence within a wave (rule #18: sched_barrier after lgkmcnt)
static __device__ __forceinline__ void wave_lds_fence() {
    asm volatile("s_waitcnt lgkmcnt(0)" ::: "memory");
    __builtin_amdgcn_sched_barrier(0);
}

// ---------------- weight pre-pack into MFMA B-fragment layout ----------------
__global__ __launch_bounds__(256) void k_pack_w(
    const float* __restrict__ eW1, const float* __restrict__ eW2,
    const float* __restrict__ nW1, const float* __restrict__ nW2,
    const float* __restrict__ oW1, const float* __restrict__ oW2,
    unsigned short* __restrict__ wpk)
{
    int t = threadIdx.x;
    int nt = t >> 6, l = t & 63;
    int kc = l >> 4, n0 = l & 15;

    #pragma unroll
    for (int j = 0; j < 8; ++j) {
        int k = kc*8 + j;
        int orig = (k < 16) ? (9 + k) : ((k < 25) ? (k - 16) : -1);
        float v = (orig >= 0) ? eW1[orig*DD + nt*16 + n0] : 0.0f;
        wpk[((size_t)((FR_E1 + nt)*64 + l))*8 + j] = f2bf(v);
    }
    #pragma unroll
    for (int s = 0; s < 2; ++s) {
        #pragma unroll
        for (int j = 0; j < 8; ++j) {
            int k = s*32 + kc*8 + j;
            wpk[((size_t)((FR_E2 + s*4 + nt)*64 + l))*8 + j] = f2bf(eW2[k*DD + nt*16 + n0]);
            wpk[((size_t)((FR_N1 + s*4 + nt)*64 + l))*8 + j] = f2bf(nW1[k*DD + nt*16 + n0]);
            wpk[((size_t)((FR_N2 + s*4 + nt)*64 + l))*8 + j] = f2bf(nW2[k*DD + nt*16 + n0]);
            wpk[((size_t)((FR_O2 + s*4 + nt)*64 + l))*8 + j] = f2bf(oW2[k*DD + nt*16 + n0]);
        }
    }
    #pragma unroll
    for (int s = 0; s < 4; ++s) {
        #pragma unroll
        for (int j = 0; j < 8; ++j) {
            int k = s*32 + kc*8 + j;
            wpk[((size_t)((FR_O1 + s*4 + nt)*64 + l))*8 + j] = f2bf(oW1[k*DD + nt*16 + n0]);
        }
    }
}

// ---------------- fused: node MLP (blocks < nb) + histogram (blocks >= nb) --
__global__ __launch_bounds__(256, 2) void k_node_hist(
    const float* __restrict__ x,
    const unsigned short* __restrict__ wpk,
    const float* __restrict__ b1, const float* __restrict__ b2,
    unsigned short* __restrict__ x_tb, int n, int nodeBlocks,
    const int* __restrict__ col, u32* __restrict__ cnt, int n_e)
{
    __shared__ __align__(16) unsigned short tile[4][16*PADH];
    const int tid  = threadIdx.x;

    if (blockIdx.x >= nodeBlocks) {
        int g = (blockIdx.x - nodeBlocks) * 256 + tid;
        int base = g * 4;
        if (base + 3 < n_e) {
            int4 c = ((const int4*)col)[g];
            atomicAdd(&cnt[c.x], 1u);
            atomicAdd(&cnt[c.y], 1u);
            atomicAdd(&cnt[c.z], 1u);
            atomicAdd(&cnt[c.w], 1u);
        } else {
            for (int e = base; e < n_e; ++e) atomicAdd(&cnt[col[e]], 1u);
        }
        return;
    }

    const int wv   = tid >> 6;
    const int lane = tid & 63;
    const int kc   = lane >> 4;
    const int n0   = lane & 15;
    const int rbase = kc * 4;

    const short8* fb = (const short8*)wpk;
    short8 bw1[2][4], bw2[2][4];
    #pragma unroll
    for (int s = 0; s < 2; ++s)
        #pragma unroll
        for (int nt = 0; nt < 4; ++nt) {
            bw1[s][nt] = fb[(FR_N1 + s*4 + nt)*64 + lane];
            bw2[s][nt] = fb[(FR_N2 + s*4 + nt)*64 + lane];
        }
    float b1v[4], b2v[4];
    #pragma unroll
    for (int nt = 0; nt < 4; ++nt) { b1v[nt] = b1[nt*16 + n0]; b2v[nt] = b2[nt*16 + n0]; }

    const int base = blockIdx.x*64 + wv*16;
    int rc = min(base + n0, n - 1);
    const float* xr = x + (size_t)rc * DD;

    short8 a[2];
    #pragma unroll
    for (int m = 0; m < 2; ++m) {
        float4 u0 = *(const float4*)(xr + m*32 + kc*8);
        float4 u1 = *(const float4*)(xr + m*32 + kc*8 + 4);
        unsigned* au = (unsigned*)&a[m];
        au[0] = cvt_pk_bf16(u0.x, u0.y);
        au[1] = cvt_pk_bf16(u0.z, u0.w);
        au[2] = cvt_pk_bf16(u1.x, u1.y);
        au[3] = cvt_pk_bf16(u1.z, u1.w);
    }

    f32x4 zz = {0.f, 0.f, 0.f, 0.f};
    f32x4 hacc[4] = {zz, zz, zz, zz};
    #pragma unroll
    for (int m = 0; m < 2; ++m)
        #pragma unroll
        for (int nt = 0; nt < 4; ++nt)
            hacc[nt] = __builtin_amdgcn_mfma_f32_16x16x32_bf16(a[m], bw1[m][nt], hacc[nt], 0, 0, 0);

    #pragma unroll
    for (int nt = 0; nt < 4; ++nt)
        #pragma unroll
        for (int r = 0; r < 4; ++r)
            tile[wv][(rbase + r)*PADH + nt*16 + n0] = f2bf(silu(hacc[nt][r] + b1v[nt]));
    __syncthreads();

    short8 a2_0 = *(const short8*)&tile[wv][n0*PADH +  0 + kc*8];
    short8 a2_1 = *(const short8*)&tile[wv][n0*PADH + 32 + kc*8];
    f32x4 oacc[4];
    #pragma unroll
    for (int nt = 0; nt < 4; ++nt) {
        oacc[nt] = __builtin_amdgcn_mfma_f32_16x16x32_bf16(a2_0, bw2[0][nt], zz, 0, 0, 0);
        oacc[nt] = __builtin_amdgcn_mfma_f32_16x16x32_bf16(a2_1, bw2[1][nt], oacc[nt], 0, 0, 0);
    }
    __syncthreads();

    #pragma unroll
    for (int nt = 0; nt < 4; ++nt)
        #pragma unroll
        for (int r = 0; r < 4; ++r)
            tile[wv][(rbase + r)*PADH + nt*16 + n0] = f2bf(oacc[nt][r] + b2v[nt]);
    __syncthreads();

    int ei = lane >> 2, q = lane & 3;
    int er = base + ei;
    if (er < n) {
        uint4* dst = (uint4*)(x_tb + (size_t)er * DD);
        dst[q]     = *(const uint4*)&tile[wv][ei*PADH + q*8];
        dst[q + 4] = *(const uint4*)&tile[wv][ei*PADH + (q + 4)*8];
    }
}

// ---------------- scans ----------------
__global__ __launch_bounds__(256) void k_scan1(
    const u32* __restrict__ cnt, u32* __restrict__ bsum, int n)
{
    __shared__ u32 s[256];
    int i = blockIdx.x * 256 + threadIdx.x;
    s[threadIdx.x] = (i < n) ? cnt[i] : 0u;
    __syncthreads();
    for (int o = 128; o > 0; o >>= 1) {
        if (threadIdx.x < o) s[threadIdx.x] += s[threadIdx.x + o];
        __syncthreads();
    }
    if (threadIdx.x == 0) bsum[blockIdx.x] = s[0];
}

__global__ __launch_bounds__(512) void k_scan2(
    const u32* __restrict__ bsum, u32* __restrict__ boff, int nb)
{
    __shared__ u32 s[512];
    int t = threadIdx.x;
    u32 v = (t < nb) ? bsum[t] : 0u;
    s[t] = v;
    __syncthreads();
    for (int o = 1; o < 512; o <<= 1) {
        u32 a = (t >= o) ? s[t - o] : 0u;
        __syncthreads();
        s[t] += a;
        __syncthreads();
    }
    if (t < nb) boff[t] = s[t] - v;
}

__global__ __launch_bounds__(256) void k_scan3(
    const u32* __restrict__ cnt, const u32* __restrict__ boff,
    u32* __restrict__ wp, int n)
{
    __shared__ u32 s[256];
    int t = threadIdx.x;
    int i = blockIdx.x * 256 + t;
    u32 v = (i < n) ? cnt[i] : 0u;
    s[t] = v;
    __syncthreads();
    for (int o = 1; o < 256; o <<= 1) {
        u32 a = (t >= o) ? s[t - o] : 0u;
        __syncthreads();
        s[t] += a;
        __syncthreads();
    }
    if (i < n) wp[i] = boff[blockIdx.x] + s[t] - v;
}

// ---------------- counting-sort scatter + agg zero ----------------
__global__ __launch_bounds__(256) void k_scatter(
    const int* __restrict__ row, const int* __restrict__ col,
    u32* __restrict__ wp, u64* __restrict__ ce,
    float* __restrict__ agg, int n_agg4, int n_e)
{
    int e = blockIdx.x * 256 + threadIdx.x;
    if (e < n_agg4) {
        float4 z = {0.f, 0.f, 0.f, 0.f};
        ((float4*)agg)[e] = z;
    }
    if (e >= n_e) return;
    int c = col[e];
    int r = row[e];
    u32 p = atomicAdd(&wp[c], 1u);
    u32 lo = (u32)e | ((u32)r << 21);
    u32 hi = ((u32)r >> 11) | ((u32)c << 6);
    u64 pk = (u64)lo | ((u64)hi << 32);
    __builtin_nontemporal_store(pk, &ce[p]);
}

// ---------------- fused edge kernel: swapped GEMMs, overlaid LDS tile -------
// 256 threads = 4 waves; wave owns 64 sorted slots, 4 sub-tiles of 16 edges.
// LDS: one 16x72 bf16 tile per wave (hid then msg overlay) + 8KB shared bw2.
// launch_bounds (256,4): VGPR cap 128 (natural ~64-80, no spill) — R12's
// (256,8) forced VGPR=32 and spilled (FETCH 224->678MB). This is the fix.
__global__ __launch_bounds__(256, 4) void k_edge_fused(
    const float* __restrict__ pos,
    const float* __restrict__ edge_attr,
    const u64* __restrict__ ce,
    const unsigned short* __restrict__ x_tb,
    const unsigned short* __restrict__ wpk,
    const float* __restrict__ b1, const float* __restrict__ b2,
    float* __restrict__ agg, int n_e)
{
    __shared__ __align__(16) unsigned short t_s[4][16*HS];   // 9216 B (hid/msg overlay)
    __shared__ __align__(16) unsigned short wls[8*64*8];     // 8192 B (edge W2 frags)

    const int tid  = threadIdx.x;
    const int wv   = tid >> 6;
    const int lane = tid & 63;
    const int kc   = lane >> 4;
    const int n0   = lane & 15;

    // stage bw2 into block-shared LDS (contiguous 8KB at wpk + FR_E2*512 shorts)
    {
        const uint4* wsrc = (const uint4*)(wpk + FR_E2*64*8);
        uint4* wdst = (uint4*)wls;
        wdst[tid*2]     = wsrc[tid*2];
        wdst[tid*2 + 1] = wsrc[tid*2 + 1];
    }

    const short8* fb = (const short8*)wpk;
    short8 bw1[4];
    #pragma unroll
    for (int nt = 0; nt < 4; ++nt) bw1[nt] = fb[(FR_E1 + nt)*64 + lane];

    // biases packed bf16: lane holds features f = nt*16 + kc*4 + r
    uint2 bp1[4], bp2[4];
    #pragma unroll
    for (int nt = 0; nt < 4; ++nt) {
        float4 q1 = *(const float4*)(b1 + nt*16 + kc*4);
        float4 q2 = *(const float4*)(b2 + nt*16 + kc*4);
        bp1[nt].x = cvt_pk_bf16(q1.x, q1.y); bp1[nt].y = cvt_pk_bf16(q1.z, q1.w);
        bp2[nt].x = cvt_pk_bf16(q2.x, q2.y); bp2[nt].y = cvt_pk_bf16(q2.z, q2.w);
    }

    const int gbase = blockIdx.x*256 + wv*64;
    int g  = gbase + lane;
    int gc = min(g, n_e - 1);
    u64 pk = ce[gc];
    u32 pklo = (u32)pk, pkhi = (u32)(pk >> 32);
    int eo = (int)(pklo & 0x1FFFFFu);
    int rw = (int)((pklo >> 21) | ((pkhi & 0x3Fu) << 11));
    int cl = (int)(pkhi >> 6);

    // ---- geometry + SH: once per edge (this lane), packed to bf16 regs ----
    float ax = pos[3*rw+0] - pos[3*cl+0];
    float ay = pos[3*rw+1] - pos[3*cl+1];
    float az = pos[3*rw+2] - pos[3*cl+2];
    float len = sqrtf(fmaf(ax,ax, fmaf(ay,ay, az*az)) + 1e-12f);
    float dx = ax/len, dy = ay/len, dz = az/len;
    float n2 = sqrtf(fmaf(dx,dx, fmaf(dy,dy, dz*dz)));
    float inv = 1.0f/(n2 + 1e-10f);
    dx *= inv; dy *= inv; dz *= inv;

    u32 shp01 = cvt_pk_bf16(0.28209479177387814f, 0.4886025119029199f*dy);
    u32 shp23 = cvt_pk_bf16(0.4886025119029199f*dz, 0.4886025119029199f*dx);
    u32 shp45 = cvt_pk_bf16(1.0925484305920792f*dx*dy, 1.0925484305920792f*dy*dz);
    u32 shp67 = cvt_pk_bf16(0.31539156525252005f*(3.0f*dz*dz - 1.0f),
                            1.0925484305920792f*dx*dz);
    u32 shp8  = cvt_pk_bf16(0.5462742152960396f*(dx*dx - dy*dy), 0.0f);

    // ---- wave-uniform flush mask ----
    int cln = bperm(min(lane + 1, 63), cl);
    u64 fmask = __ballot(cln != cl) | 0x8000800080008000ull;

    f32x4 zz = {0.f, 0.f, 0.f, 0.f};

    __syncthreads();   // wls staged (once per block)

    #pragma unroll 1
    for (int tt = 0; tt < 4; ++tt) {
        const int le = tt*16 + n0;
        bool valid = (gbase + le) < n_e;

        // cross-lane broadcasts + global gathers
        int ea  = bperm(le, eo);
        int rv  = bperm(le, rw);
        u32 s01 = (u32)bperm(le, (int)shp01);
        u32 s23 = (u32)bperm(le, (int)shp23);
        u32 s45 = (u32)bperm(le, (int)shp45);
        u32 s67 = (u32)bperm(le, (int)shp67);
        u32 s8  = (u32)bperm(le, (int)shp8);

        const unsigned short* xrow = x_tb + (size_t)rv * DD;
        uint2 xv0 = *(const uint2*)(xrow +  0 + kc*4);
        uint2 xv1 = *(const uint2*)(xrow + 16 + kc*4);
        uint2 xv2 = *(const uint2*)(xrow + 32 + kc*4);
        uint2 xv3 = *(const uint2*)(xrow + 48 + kc*4);

        // feature B-frag: lane holds F[e = le][k = kc*8 + j]
        short8 af;
        unsigned* au = (unsigned*)&af;
        if (kc < 2) {
            const float4* ap = (const float4*)(edge_attr + (size_t)ea*EDA + kc*8);
            float4 a0 = ap[0], a1 = ap[1];
            au[0] = cvt_pk_bf16(a0.x, a0.y);
            au[1] = cvt_pk_bf16(a0.z, a0.w);
            au[2] = cvt_pk_bf16(a1.x, a1.y);
            au[3] = cvt_pk_bf16(a1.z, a1.w);
        } else if (kc == 2) {
            au[0] = s01; au[1] = s23; au[2] = s45; au[3] = s67;
        } else {
            au[0] = s8; au[1] = 0u; au[2] = 0u; au[3] = 0u;
        }

        // GEMM1 swapped: lane gets hid[e=n0][f=nt*16+kc*4+r]
        f32x4 hacc[4];
        #pragma unroll
        for (int nt = 0; nt < 4; ++nt)
            hacc[nt] = __builtin_amdgcn_mfma_f32_16x16x32_bf16(bw1[nt], af, zz, 0, 0, 0);

        #pragma unroll
        for (int nt = 0; nt < 4; ++nt) {
            float h0 = silu(hacc[nt][0] + bflo(bp1[nt].x));
            float h1 = silu(hacc[nt][1] + bfhi(bp1[nt].x));
            float h2 = silu(hacc[nt][2] + bflo(bp1[nt].y));
            float h3 = silu(hacc[nt][3] + bfhi(bp1[nt].y));
            uint2 pr;
            pr.x = cvt_pk_bf16(h0, h1);
            pr.y = cvt_pk_bf16(h2, h3);
            *(uint2*)&t_s[wv][n0*HS + nt*16 + kc*4] = pr;
        }
        wave_lds_fence();

        // GEMM2 swapped: W2 fragments from block-shared LDS
        short8 bf0 = *(const short8*)&t_s[wv][n0*HS +  0 + kc*8];
        short8 bf1 = *(const short8*)&t_s[wv][n0*HS + 32 + kc*8];
        f32x4 oacc[4];
        #pragma unroll
        for (int nt = 0; nt < 4; ++nt) {
            short8 w0 = *(const short8*)&wls[((0*4 + nt)*64 + lane)*8];
            oacc[nt] = __builtin_amdgcn_mfma_f32_16x16x32_bf16(w0, bf0, zz, 0, 0, 0);
            short8 w1 = *(const short8*)&wls[((1*4 + nt)*64 + lane)*8];
            oacc[nt] = __builtin_amdgcn_mfma_f32_16x16x32_bf16(w1, bf1, oacc[nt], 0, 0, 0);
        }

        // epilogue: msg (bf16, overlaid on t_s) = (out + b2) * x_t[row]; zero invalid
        if (!valid) {
            xv0.x = xv0.y = xv1.x = xv1.y = 0u;
            xv2.x = xv2.y = xv3.x = xv3.y = 0u;
        }
        {
            float m0, m1, m2, m3;
            uint2 pr;
            m0 = (oacc[0][0] + bflo(bp2[0].x)) * bflo(xv0.x);
            m1 = (oacc[0][1] + bfhi(bp2[0].x)) * bfhi(xv0.x);
            m2 = (oacc[0][2] + bflo(bp2[0].y)) * bflo(xv0.y);
            m3 = (oacc[0][3] + bfhi(bp2[0].y)) * bfhi(xv0.y);
            pr.x = cvt_pk_bf16(m0, m1); pr.y = cvt_pk_bf16(m2, m3);
            *(uint2*)&t_s[wv][n0*HS +  0 + kc*4] = pr;
            m0 = (oacc[1][0] + bflo(bp2[1].x)) * bflo(xv1.x);
            m1 = (oacc[1][1] + bfhi(bp2[1].x)) * bfhi(xv1.x);
            m2 = (oacc[1][2] + bflo(bp2[1].y)) * bflo(xv1.y);
            m3 = (oacc[1][3] + bfhi(bp2[1].y)) * bfhi(xv1.y);
            pr.x = cvt_pk_bf16(m0, m1); pr.y = cvt_pk_bf16(m2, m3);
            *(uint2*)&t_s[wv][n0*HS + 16 + kc*4] = pr;
            m0 = (oacc[2][0] + bflo(bp2[2].x)) * bflo(xv2.x);
            m1 = (oacc[2][1] + bfhi(bp2[2].x)) * bfhi(xv2.x);
            m2 = (oacc[2][2] + bflo(bp2[2].y)) * bflo(xv2.y);
            m3 = (oacc[2][3] + bfhi(bp2[2].y)) * bfhi(xv2.y);
            pr.x = cvt_pk_bf16(m0, m1); pr.y = cvt_pk_bf16(m2, m3);
            *(uint2*)&t_s[wv][n0*HS + 32 + kc*4] = pr;
            m0 = (oacc[3][0] + bflo(bp2[3].x)) * bflo(xv3.x);
            m1 = (oacc[3][1] + bfhi(bp2[3].x)) * bfhi(xv3.x);
            m2 = (oacc[3][2] + bflo(bp2[3].y)) * bflo(xv3.y);
            m3 = (oacc[3][3] + bfhi(bp2[3].y)) * bfhi(xv3.y);
            pr.x = cvt_pk_bf16(m0, m1); pr.y = cvt_pk_bf16(m2, m3);
            *(uint2*)&t_s[wv][n0*HS + 48 + kc*4] = pr;
        }
        wave_lds_fence();

        // segmented reduce: lane = feature; scalar flush test via fmask
        {
            float acc = 0.0f;
            #pragma unroll
            for (int r = 0; r < 16; ++r) {
                acc += bf2f(t_s[wv][r*HS + lane]);
                if ((fmask >> (tt*16 + r)) & 1ull) {     // wave-uniform branch
                    int cur = __builtin_amdgcn_readlane(cl, tt*16 + r);
                    unsafeAtomicAdd(&agg[(size_t)cur*DD + lane], acc);
                    acc = 0.0f;
                }
            }
        }
    }
}

// ---------------- MFMA out MLP (+ /cnt) + fused BN partial sums ----------------
__global__ __launch_bounds__(256, 2) void k_out_mfma(
    const float* __restrict__ agg, const u32* __restrict__ cnt,
    const float* __restrict__ x,
    const unsigned short* __restrict__ wpk,
    const float* __restrict__ b1, const float* __restrict__ b2,
    float* __restrict__ h, float* __restrict__ sums, int n)
{
    __shared__ __align__(16) unsigned short htile[4][16*PADH];
    __shared__ __align__(16) float otile[4][16*PADF];
    const int tid  = threadIdx.x;
    const int wv   = tid >> 6;
    const int lane = tid & 63;
    const int kc   = lane >> 4;
    const int n0   = lane & 15;
    const int rbase = kc * 4;

    const short8* fb = (const short8*)wpk;
    short8 bw1[4][4], bw2[2][4];
    #pragma unroll
    for (int s = 0; s < 4; ++s)
        #pragma unroll
        for (int nt = 0; nt < 4; ++nt) bw1[s][nt] = fb[(FR_O1 + s*4 + nt)*64 + lane];
    #pragma unroll
    for (int s = 0; s < 2; ++s)
        #pragma unroll
        for (int nt = 0; nt < 4; ++nt) bw2[s][nt] = fb[(FR_O2 + s*4 + nt)*64 + lane];

    float b1v[4], b2v[4];
    #pragma unroll
    for (int nt = 0; nt < 4; ++nt) { b1v[nt] = b1[nt*16 + n0]; b2v[nt] = b2[nt*16 + n0]; }

    const int base = blockIdx.x*64 + wv*16;
    int rc = min(base + n0, n - 1);
    const float* ar = agg + (size_t)rc * DD;
    const float* xr = x   + (size_t)rc * DD;
    float invc = 1.0f / fmaxf((float)cnt[rc], 1.0f);

    short8 a[4];
    #pragma unroll
    for (int m = 0; m < 4; ++m) {
        const float* src = (m < 2) ? (ar + m*32 + kc*8) : (xr + (m-2)*32 + kc*8);
        float4 u0 = *(const float4*)(src);
        float4 u1 = *(const float4*)(src + 4);
        if (m < 2) {
            u0.x*=invc; u0.y*=invc; u0.z*=invc; u0.w*=invc;
            u1.x*=invc; u1.y*=invc; u1.z*=invc; u1.w*=invc;
        }
        unsigned* au = (unsigned*)&a[m];
        au[0] = cvt_pk_bf16(u0.x, u0.y);
        au[1] = cvt_pk_bf16(u0.z, u0.w);
        au[2] = cvt_pk_bf16(u1.x, u1.y);
        au[3] = cvt_pk_bf16(u1.z, u1.w);
    }

    f32x4 zz = {0.f, 0.f, 0.f, 0.f};
    f32x4 hacc[4] = {zz, zz, zz, zz};
    #pragma unroll
    for (int m = 0; m < 4; ++m)
        #pragma unroll
        for (int nt = 0; nt < 4; ++nt)
            hacc[nt] = __builtin_amdgcn_mfma_f32_16x16x32_bf16(a[m], bw1[m][nt], hacc[nt], 0, 0, 0);

    #pragma unroll
    for (int nt = 0; nt < 4; ++nt)
        #pragma unroll
        for (int r = 0; r < 4; ++r)
            htile[wv][(rbase + r)*PADH + nt*16 + n0] = f2bf(silu(hacc[nt][r] + b1v[nt]));
    __syncthreads();

    short8 a2_0 = *(const short8*)&htile[wv][n0*PADH +  0 + kc*8];
    short8 a2_1 = *(const short8*)&htile[wv][n0*PADH + 32 + kc*8];
    f32x4 oacc[4];
    #pragma unroll
    for (int nt = 0; nt < 4; ++nt) {
        oacc[nt] = __builtin_amdgcn_mfma_f32_16x16x32_bf16(a2_0, bw2[0][nt], zz, 0, 0, 0);
        oacc[nt] = __builtin_amdgcn_mfma_f32_16x16x32_bf16(a2_1, bw2[1][nt], oacc[nt], 0, 0, 0);
    }

    #pragma unroll
    for (int nt = 0; nt < 4; ++nt)
        #pragma unroll
        for (int r = 0; r < 4; ++r)
            otile[wv][(rbase + r)*PADF + nt*16 + n0] = oacc[nt][r] + b2v[nt];
    __syncthreads();

    int ei = lane >> 2, q = lane & 3;
    int er = base + ei;
    if (er < n) {
        float4* dst = (float4*)(h + (size_t)er * DD);
        #pragma unroll
        for (int k = 0; k < 4; ++k)
            dst[q + 4*k] = *(const float4*)&otile[wv][ei*PADF + (q + 4*k)*4];
    }

    if (tid < 64) {
        int f = tid;
        float s = 0.f, qq = 0.f;
        #pragma unroll
        for (int w = 0; w < 4; ++w) {
            int base_w = blockIdx.x*64 + w*16;
            int nv = n - base_w;
            nv = nv < 0 ? 0 : (nv > 16 ? 16 : nv);
            for (int r = 0; r < nv; ++r) {
                float v = otile[w][r*PADF + f];
                s += v; qq = fmaf(v, v, qq);
            }
        }
        unsafeAtomicAdd(&sums[f], s);
        unsafeAtomicAdd(&sums[DD + f], qq);
    }
}

// ---------------- BN normalize (finalize fused in) ----------------
__global__ __launch_bounds__(256) void k_bn_norm(
    float* __restrict__ h, const float* __restrict__ sums,
    const float* __restrict__ gamma, const float* __restrict__ beta,
    float inv_n, int total4)
{
    int g = blockIdx.x*256 + threadIdx.x;
    if (g >= total4) return;
    int f0 = (g*4) & (DD-1);
    float4 v = ((const float4*)h)[g];
    float4 sm = *(const float4*)(sums + f0);
    float4 sq = *(const float4*)(sums + DD + f0);
    float4 gm = *(const float4*)(gamma + f0);
    float4 bt = *(const float4*)(beta + f0);
    float m0 = sm.x*inv_n, m1 = sm.y*inv_n, m2 = sm.z*inv_n, m3 = sm.w*inv_n;
    float s0 = gm.x * rsqrtf(sq.x*inv_n - m0*m0 + 1e-5f);
    float s1 = gm.y * rsqrtf(sq.y*inv_n - m1*m1 + 1e-5f);
    float s2 = gm.z * rsqrtf(sq.z*inv_n - m2*m2 + 1e-5f);
    float s3 = gm.w * rsqrtf(sq.w*inv_n - m3*m3 + 1e-5f);
    v.x = fmaf(v.x - m0, s0, bt.x);
    v.y = fmaf(v.y - m1, s1, bt.y);
    v.z = fmaf(v.z - m2, s2, bt.z);
    v.w = fmaf(v.w - m3, s3, bt.w);
    ((float4*)h)[g] = v;
}

static inline size_t al16(size_t v) { return (v + 15) & ~(size_t)15; }

extern "C" void kernel_launch(void* const* d_in, const int* in_sizes, int n_in,
                              void* d_out, int out_size, void* d_ws, size_t ws_size,
                              hipStream_t stream)
{
    const float* x         = (const float*)d_in[0];
    const float* pos       = (const float*)d_in[1];
    const float* edge_attr = (const float*)d_in[2];
    const int*   row       = (const int*)d_in[3];
    const int*   col       = (const int*)d_in[4];
    const float* nW1 = (const float*)d_in[5];
    const float* nb1 = (const float*)d_in[6];
    const float* nW2 = (const float*)d_in[7];
    const float* nb2 = (const float*)d_in[8];
    const float* eW1 = (const float*)d_in[9];
    const float* eb1 = (const float*)d_in[10];
    const float* eW2 = (const float*)d_in[11];
    const float* eb2 = (const float*)d_in[12];
    const float* oW1 = (const float*)d_in[13];
    const float* ob1 = (const float*)d_in[14];
    const float* oW2 = (const float*)d_in[15];
    const float* ob2 = (const float*)d_in[16];
    const float* gamma = (const float*)d_in[17];
    const float* beta  = (const float*)d_in[18];

    const int N = in_sizes[0] / DD;   // 100000  (< 2^17 for packing)
    const int E = in_sizes[3];        // 1600000 (< 2^21 for packing)
    const int NB = (N + 255) / 256;   // 391
    const int nodeBlocks = (N + 63) / 64;       // 1563
    const int histBlocks = (E/4 + 255) / 256;   // 1563

    float* hout = (float*)d_out;
    char* ws = (char*)d_ws;

    size_t o_xtb  = 0;
    size_t o_cnt  = o_xtb  + (size_t)N*DD*2;
    size_t o_sums = o_cnt  + (size_t)N*4;
    size_t o_agg  = o_sums + 128*4;
    size_t o_wp   = o_agg  + (size_t)N*DD*4;
    size_t o_bsum = o_wp   + (size_t)N*4;
    size_t o_boff = al16(o_bsum + (size_t)NB*4);
    size_t o_wpk  = al16(o_boff + (size_t)NB*4);
    size_t o_ce   = al16(o_wpk + (size_t)FR_TOT*64*8*2);
    size_t need   = o_ce + (size_t)E*8;

    if (ws_size < need) return;

    unsigned short* x_tb = (unsigned short*)(ws + o_xtb);
    u32*   cnt  = (u32*)(ws + o_cnt);
    float* sums = (float*)(ws + o_sums);
    float* agg  = (float*)(ws + o_agg);
    u32*   wp   = (u32*)(ws + o_wp);
    u32*   bsum = (u32*)(ws + o_bsum);
    u32*   boff = (u32*)(ws + o_boff);
    unsigned short* wpk = (unsigned short*)(ws + o_wpk);
    u64*   ce   = (u64*)(ws + o_ce);

    // zero cnt + sums only (agg zeroed inside k_scatter)
    hipMemsetAsync(cnt, 0, (size_t)N*4 + 128*4, stream);

    k_pack_w<<<1, 256, 0, stream>>>(eW1, eW2, nW1, nW2, oW1, oW2, wpk);
    k_node_hist<<<nodeBlocks + histBlocks, 256, 0, stream>>>(
        x, wpk, nb1, nb2, x_tb, N, nodeBlocks, col, cnt, E);
    k_scan1<<<NB, 256, 0, stream>>>(cnt, bsum, N);
    k_scan2<<<1, 512, 0, stream>>>(bsum, boff, NB);
    k_scan3<<<NB, 256, 0, stream>>>(cnt, boff, wp, N);
    k_scatter<<<(E + 255)/256, 256, 0, stream>>>(row, col, wp, ce, agg, N*DD/4, E);
    k_edge_fused<<<(E + 255)/256, 256, 0, stream>>>(pos, edge_attr, ce, x_tb,
                                                    wpk, eb1, eb2, agg, E);
    k_out_mfma<<<(N + 63)/64, 256, 0, stream>>>(agg, cnt, x, wpk, ob1, ob2, hout, sums, N);
    k_bn_norm<<<(N*DD/4 + 255)/256, 256, 0, stream>>>(hout, sums, gamma, beta,
                                                      1.0f/(float)N, N*DD/4);
}

// Round 14
// 326.910 us; speedup vs baseline: 1.5360x; 1.0332x over previous
//
#include <hip/hip_runtime.h>
#include <math.h>

#define DD 64
#define EDA 16

// packed B-fragment offsets (units of 64-lane short8 entries)
#define FR_E1 0
#define FR_E2 4
#define FR_N1 12
#define FR_N2 20
#define FR_O1 28
#define FR_O2 44
#define FR_TOT 52

#define PADH 72   // hid bf16 LDS row stride (ushort) for node/out kernels
#define PADF 68   // f32 LDS row stride (float)

// edge kernel strides
#define HS 72     // unified tile row stride in ushort (144B; %16==0 for b128)

typedef unsigned int u32;
typedef unsigned long long u64;
typedef __attribute__((ext_vector_type(8))) short short8;
typedef __attribute__((ext_vector_type(4))) float f32x4;

static __device__ __forceinline__ float silu(float v) {
    return v / (1.0f + __expf(-v));
}
static __device__ __forceinline__ unsigned short f2bf(float f) {
    unsigned u = __float_as_uint(f);
    unsigned r = u + 0x7FFFu + ((u >> 16) & 1u);   // RNE
    return (unsigned short)(r >> 16);
}
static __device__ __forceinline__ float bf2f(unsigned short u) {
    return __uint_as_float(((unsigned)u) << 16);
}
static __device__ __forceinline__ float bflo(u32 v) {
    return __uint_as_float(v << 16);
}
static __device__ __forceinline__ float bfhi(u32 v) {
    return __uint_as_float(v & 0xFFFF0000u);
}
static __device__ __forceinline__ unsigned cvt_pk_bf16(float lo, float hi) {
    unsigned r;
    asm("v_cvt_pk_bf16_f32 %0, %1, %2" : "=v"(r) : "v"(lo), "v"(hi));
    return r;
}
static __device__ __forceinline__ int bperm(int idx_lane, int v) {
    return __builtin_amdgcn_ds_bpermute(idx_lane << 2, v);
}
// LDS write->read fence within a wave (rule #18: sched_barrier after lgkmcnt)
static __device__ __forceinline__ void wave_lds_fence() {
    asm volatile("s_waitcnt lgkmcnt(0)" ::: "memory");
    __builtin_amdgcn_sched_barrier(0);
}

// ---------------- weight pre-pack (block 0) + workspace zero (blocks >=1) ----
__global__ __launch_bounds__(256) void k_pack_zero(
    const float* __restrict__ eW1, const float* __restrict__ eW2,
    const float* __restrict__ nW1, const float* __restrict__ nW2,
    const float* __restrict__ oW1, const float* __restrict__ oW2,
    unsigned short* __restrict__ wpk,
    uint4* __restrict__ zbase, int nz4)
{
    if (blockIdx.x > 0) {
        int i = (blockIdx.x - 1) * 256 + threadIdx.x;
        if (i < nz4) zbase[i] = make_uint4(0u, 0u, 0u, 0u);
        return;
    }
    int t = threadIdx.x;
    int nt = t >> 6, l = t & 63;
    int kc = l >> 4, n0 = l & 15;

    #pragma unroll
    for (int j = 0; j < 8; ++j) {
        int k = kc*8 + j;
        int orig = (k < 16) ? (9 + k) : ((k < 25) ? (k - 16) : -1);
        float v = (orig >= 0) ? eW1[orig*DD + nt*16 + n0] : 0.0f;
        wpk[((size_t)((FR_E1 + nt)*64 + l))*8 + j] = f2bf(v);
    }
    #pragma unroll
    for (int s = 0; s < 2; ++s) {
        #pragma unroll
        for (int j = 0; j < 8; ++j) {
            int k = s*32 + kc*8 + j;
            wpk[((size_t)((FR_E2 + s*4 + nt)*64 + l))*8 + j] = f2bf(eW2[k*DD + nt*16 + n0]);
            wpk[((size_t)((FR_N1 + s*4 + nt)*64 + l))*8 + j] = f2bf(nW1[k*DD + nt*16 + n0]);
            wpk[((size_t)((FR_N2 + s*4 + nt)*64 + l))*8 + j] = f2bf(nW2[k*DD + nt*16 + n0]);
            wpk[((size_t)((FR_O2 + s*4 + nt)*64 + l))*8 + j] = f2bf(oW2[k*DD + nt*16 + n0]);
        }
    }
    #pragma unroll
    for (int s = 0; s < 4; ++s) {
        #pragma unroll
        for (int j = 0; j < 8; ++j) {
            int k = s*32 + kc*8 + j;
            wpk[((size_t)((FR_O1 + s*4 + nt)*64 + l))*8 + j] = f2bf(oW1[k*DD + nt*16 + n0]);
        }
    }
}

// ---------------- fused: node MLP (blocks < nb) + histogram (blocks >= nb) --
// node output x_tb written in PERMUTED feature order: pos = kc*16 + nt*4 + r
// for feature f = nt*16 + kc*4 + r  (edge-kernel fragment-friendly layout).
__global__ __launch_bounds__(256, 3) void k_node_hist(
    const float* __restrict__ x,
    const unsigned short* __restrict__ wpk,
    const float* __restrict__ b1, const float* __restrict__ b2,
    unsigned short* __restrict__ x_tb, int n, int nodeBlocks,
    const int* __restrict__ col, u32* __restrict__ cnt, int n_e)
{
    __shared__ __align__(16) unsigned short tile[4][16*PADH];
    const int tid  = threadIdx.x;

    if (blockIdx.x >= nodeBlocks) {
        int g = (blockIdx.x - nodeBlocks) * 256 + tid;
        int base = g * 4;
        if (base + 3 < n_e) {
            int4 c = ((const int4*)col)[g];
            atomicAdd(&cnt[c.x], 1u);
            atomicAdd(&cnt[c.y], 1u);
            atomicAdd(&cnt[c.z], 1u);
            atomicAdd(&cnt[c.w], 1u);
        } else {
            for (int e = base; e < n_e; ++e) atomicAdd(&cnt[col[e]], 1u);
        }
        return;
    }

    const int wv   = tid >> 6;
    const int lane = tid & 63;
    const int kc   = lane >> 4;
    const int n0   = lane & 15;
    const int rbase = kc * 4;

    const short8* fb = (const short8*)wpk;
    short8 bw1[2][4], bw2[2][4];
    #pragma unroll
    for (int s = 0; s < 2; ++s)
        #pragma unroll
        for (int nt = 0; nt < 4; ++nt) {
            bw1[s][nt] = fb[(FR_N1 + s*4 + nt)*64 + lane];
            bw2[s][nt] = fb[(FR_N2 + s*4 + nt)*64 + lane];
        }
    float b1v[4], b2v[4];
    #pragma unroll
    for (int nt = 0; nt < 4; ++nt) { b1v[nt] = b1[nt*16 + n0]; b2v[nt] = b2[nt*16 + n0]; }

    const int base = blockIdx.x*64 + wv*16;
    int rc = min(base + n0, n - 1);
    const float* xr = x + (size_t)rc * DD;

    short8 a[2];
    #pragma unroll
    for (int m = 0; m < 2; ++m) {
        float4 u0 = *(const float4*)(xr + m*32 + kc*8);
        float4 u1 = *(const float4*)(xr + m*32 + kc*8 + 4);
        unsigned* au = (unsigned*)&a[m];
        au[0] = cvt_pk_bf16(u0.x, u0.y);
        au[1] = cvt_pk_bf16(u0.z, u0.w);
        au[2] = cvt_pk_bf16(u1.x, u1.y);
        au[3] = cvt_pk_bf16(u1.z, u1.w);
    }

    f32x4 zz = {0.f, 0.f, 0.f, 0.f};
    f32x4 hacc[4] = {zz, zz, zz, zz};
    #pragma unroll
    for (int m = 0; m < 2; ++m)
        #pragma unroll
        for (int nt = 0; nt < 4; ++nt)
            hacc[nt] = __builtin_amdgcn_mfma_f32_16x16x32_bf16(a[m], bw1[m][nt], hacc[nt], 0, 0, 0);

    #pragma unroll
    for (int nt = 0; nt < 4; ++nt)
        #pragma unroll
        for (int r = 0; r < 4; ++r)
            tile[wv][(rbase + r)*PADH + nt*16 + n0] = f2bf(silu(hacc[nt][r] + b1v[nt]));
    __syncthreads();

    short8 a2_0 = *(const short8*)&tile[wv][n0*PADH +  0 + kc*8];
    short8 a2_1 = *(const short8*)&tile[wv][n0*PADH + 32 + kc*8];
    f32x4 oacc[4];
    #pragma unroll
    for (int nt = 0; nt < 4; ++nt) {
        oacc[nt] = __builtin_amdgcn_mfma_f32_16x16x32_bf16(a2_0, bw2[0][nt], zz, 0, 0, 0);
        oacc[nt] = __builtin_amdgcn_mfma_f32_16x16x32_bf16(a2_1, bw2[1][nt], oacc[nt], 0, 0, 0);
    }
    __syncthreads();

    // PERMUTED write: feature f = nt*16 + n0 -> pos = (n0>>2)*16 + nt*4 + (n0&3)
    #pragma unroll
    for (int nt = 0; nt < 4; ++nt)
        #pragma unroll
        for (int r = 0; r < 4; ++r)
            tile[wv][(rbase + r)*PADH + (n0>>2)*16 + nt*4 + (n0&3)] =
                f2bf(oacc[nt][r] + b2v[nt]);
    __syncthreads();

    int ei = lane >> 2, q = lane & 3;
    int er = base + ei;
    if (er < n) {
        uint4* dst = (uint4*)(x_tb + (size_t)er * DD);
        dst[q]     = *(const uint4*)&tile[wv][ei*PADH + q*8];
        dst[q + 4] = *(const uint4*)&tile[wv][ei*PADH + (q + 4)*8];
    }
}

// ---------------- single-pass scan (atomic bump; segment order arbitrary) ----
__global__ __launch_bounds__(256) void k_scan_bump(
    const u32* __restrict__ cnt, u32* __restrict__ wp,
    u32* __restrict__ gctr, int n)
{
    __shared__ u32 s[256];
    __shared__ u32 base;
    int t = threadIdx.x;
    int i = blockIdx.x * 256 + t;
    u32 v = (i < n) ? cnt[i] : 0u;
    s[t] = v;
    __syncthreads();
    for (int o = 1; o < 256; o <<= 1) {
        u32 a = (t >= o) ? s[t - o] : 0u;
        __syncthreads();
        s[t] += a;
        __syncthreads();
    }
    if (t == 255) base = atomicAdd(gctr, s[255]);
    __syncthreads();
    if (i < n) wp[i] = base + s[t] - v;
}

// ---------------- counting-sort scatter + agg zero ----------------
__global__ __launch_bounds__(256) void k_scatter(
    const int* __restrict__ row, const int* __restrict__ col,
    u32* __restrict__ wp, u64* __restrict__ ce,
    float* __restrict__ agg, int n_agg4, int n_e)
{
    int e = blockIdx.x * 256 + threadIdx.x;
    if (e < n_agg4) {
        float4 z = {0.f, 0.f, 0.f, 0.f};
        ((float4*)agg)[e] = z;
    }
    if (e >= n_e) return;
    int c = col[e];
    int r = row[e];
    u32 p = atomicAdd(&wp[c], 1u);
    u32 lo = (u32)e | ((u32)r << 21);
    u32 hi = ((u32)r >> 11) | ((u32)c << 6);
    u64 pk = (u64)lo | ((u64)hi << 32);
    __builtin_nontemporal_store(pk, &ce[p]);
}

// ---------------- fused edge kernel: swapped GEMMs, overlaid LDS tile -------
// 256 threads = 4 waves; wave owns 64 sorted slots, 4 sub-tiles of 16 edges.
__global__ __launch_bounds__(256, 4) void k_edge_fused(
    const float* __restrict__ pos,
    const float* __restrict__ edge_attr,
    const u64* __restrict__ ce,
    const unsigned short* __restrict__ x_tb,
    const unsigned short* __restrict__ wpk,
    const float* __restrict__ b1, const float* __restrict__ b2,
    float* __restrict__ agg, int n_e)
{
    __shared__ __align__(16) unsigned short t_s[4][16*HS];   // 9216 B (hid/msg overlay)
    __shared__ __align__(16) unsigned short wls[8*64*8];     // 8192 B (edge W2 frags)

    const int tid  = threadIdx.x;
    const int wv   = tid >> 6;
    const int lane = tid & 63;
    const int kc   = lane >> 4;
    const int n0   = lane & 15;

    // stage bw2 into block-shared LDS
    {
        const uint4* wsrc = (const uint4*)(wpk + FR_E2*64*8);
        uint4* wdst = (uint4*)wls;
        wdst[tid*2]     = wsrc[tid*2];
        wdst[tid*2 + 1] = wsrc[tid*2 + 1];
    }

    const short8* fb = (const short8*)wpk;
    short8 bw1[4];
    #pragma unroll
    for (int nt = 0; nt < 4; ++nt) bw1[nt] = fb[(FR_E1 + nt)*64 + lane];

    // biases packed bf16: lane holds features f = nt*16 + kc*4 + r
    uint2 bp1[4], bp2[4];
    #pragma unroll
    for (int nt = 0; nt < 4; ++nt) {
        float4 q1 = *(const float4*)(b1 + nt*16 + kc*4);
        float4 q2 = *(const float4*)(b2 + nt*16 + kc*4);
        bp1[nt].x = cvt_pk_bf16(q1.x, q1.y); bp1[nt].y = cvt_pk_bf16(q1.z, q1.w);
        bp2[nt].x = cvt_pk_bf16(q2.x, q2.y); bp2[nt].y = cvt_pk_bf16(q2.z, q2.w);
    }

    const int gbase = blockIdx.x*256 + wv*64;
    int g  = gbase + lane;
    int gc = min(g, n_e - 1);
    u64 pk = ce[gc];
    u32 pklo = (u32)pk, pkhi = (u32)(pk >> 32);
    int eo = (int)(pklo & 0x1FFFFFu);
    int rw = (int)((pklo >> 21) | ((pkhi & 0x3Fu) << 11));
    int cl = (int)(pkhi >> 6);

    // ---- geometry + SH: once per edge (this lane), packed to bf16 regs ----
    float ax = pos[3*rw+0] - pos[3*cl+0];
    float ay = pos[3*rw+1] - pos[3*cl+1];
    float az = pos[3*rw+2] - pos[3*cl+2];
    float len = sqrtf(fmaf(ax,ax, fmaf(ay,ay, az*az)) + 1e-12f);
    float dx = ax/len, dy = ay/len, dz = az/len;
    float n2 = sqrtf(fmaf(dx,dx, fmaf(dy,dy, dz*dz)));
    float inv = 1.0f/(n2 + 1e-10f);
    dx *= inv; dy *= inv; dz *= inv;

    u32 shp01 = cvt_pk_bf16(0.28209479177387814f, 0.4886025119029199f*dy);
    u32 shp23 = cvt_pk_bf16(0.4886025119029199f*dz, 0.4886025119029199f*dx);
    u32 shp45 = cvt_pk_bf16(1.0925484305920792f*dx*dy, 1.0925484305920792f*dy*dz);
    u32 shp67 = cvt_pk_bf16(0.31539156525252005f*(3.0f*dz*dz - 1.0f),
                            1.0925484305920792f*dx*dz);
    u32 shp8  = cvt_pk_bf16(0.5462742152960396f*(dx*dx - dy*dy), 0.0f);

    // ---- wave-uniform flush mask ----
    int cln = bperm(min(lane + 1, 63), cl);
    u64 fmask = __ballot(cln != cl) | 0x8000800080008000ull;

    f32x4 zz = {0.f, 0.f, 0.f, 0.f};

    __syncthreads();   // wls staged (once per block)

    #pragma unroll 1
    for (int tt = 0; tt < 4; ++tt) {
        const int le = tt*16 + n0;
        bool valid = (gbase + le) < n_e;

        // cross-lane broadcasts + global gathers
        int ea  = bperm(le, eo);
        int rv  = bperm(le, rw);
        u32 s01 = (u32)bperm(le, (int)shp01);
        u32 s23 = (u32)bperm(le, (int)shp23);
        u32 s45 = (u32)bperm(le, (int)shp45);
        u32 s67 = (u32)bperm(le, (int)shp67);
        u32 s8  = (u32)bperm(le, (int)shp8);

        // x_tb permuted layout: lane's 16 features are contiguous at kc*16
        const unsigned short* xrow = x_tb + (size_t)rv * DD + kc*16;
        uint4 qa = *(const uint4*)(xrow);
        uint4 qb = *(const uint4*)(xrow + 8);
        uint2 xv0 = {qa.x, qa.y}, xv1 = {qa.z, qa.w};
        uint2 xv2 = {qb.x, qb.y}, xv3 = {qb.z, qb.w};

        // feature B-frag: lane holds F[e = le][k = kc*8 + j]
        short8 af;
        unsigned* au = (unsigned*)&af;
        if (kc < 2) {
            const float4* ap = (const float4*)(edge_attr + (size_t)ea*EDA + kc*8);
            float4 a0 = ap[0], a1 = ap[1];
            au[0] = cvt_pk_bf16(a0.x, a0.y);
            au[1] = cvt_pk_bf16(a0.z, a0.w);
            au[2] = cvt_pk_bf16(a1.x, a1.y);
            au[3] = cvt_pk_bf16(a1.z, a1.w);
        } else if (kc == 2) {
            au[0] = s01; au[1] = s23; au[2] = s45; au[3] = s67;
        } else {
            au[0] = s8; au[1] = 0u; au[2] = 0u; au[3] = 0u;
        }

        // GEMM1 swapped: lane gets hid[e=n0][f=nt*16+kc*4+r]
        f32x4 hacc[4];
        #pragma unroll
        for (int nt = 0; nt < 4; ++nt)
            hacc[nt] = __builtin_amdgcn_mfma_f32_16x16x32_bf16(bw1[nt], af, zz, 0, 0, 0);

        #pragma unroll
        for (int nt = 0; nt < 4; ++nt) {
            float h0 = silu(hacc[nt][0] + bflo(bp1[nt].x));
            float h1 = silu(hacc[nt][1] + bfhi(bp1[nt].x));
            float h2 = silu(hacc[nt][2] + bflo(bp1[nt].y));
            float h3 = silu(hacc[nt][3] + bfhi(bp1[nt].y));
            uint2 pr;
            pr.x = cvt_pk_bf16(h0, h1);
            pr.y = cvt_pk_bf16(h2, h3);
            *(uint2*)&t_s[wv][n0*HS + nt*16 + kc*4] = pr;
        }
        wave_lds_fence();

        // GEMM2 swapped: W2 fragments from block-shared LDS
        short8 bf0 = *(const short8*)&t_s[wv][n0*HS +  0 + kc*8];
        short8 bf1 = *(const short8*)&t_s[wv][n0*HS + 32 + kc*8];
        f32x4 oacc[4];
        #pragma unroll
        for (int nt = 0; nt < 4; ++nt) {
            short8 w0 = *(const short8*)&wls[((0*4 + nt)*64 + lane)*8];
            oacc[nt] = __builtin_amdgcn_mfma_f32_16x16x32_bf16(w0, bf0, zz, 0, 0, 0);
            short8 w1 = *(const short8*)&wls[((1*4 + nt)*64 + lane)*8];
            oacc[nt] = __builtin_amdgcn_mfma_f32_16x16x32_bf16(w1, bf1, oacc[nt], 0, 0, 0);
        }

        // epilogue: msg (bf16, overlaid on t_s) = (out + b2) * x_t[row]; zero invalid
        if (!valid) {
            xv0.x = xv0.y = xv1.x = xv1.y = 0u;
            xv2.x = xv2.y = xv3.x = xv3.y = 0u;
        }
        {
            float m0, m1, m2, m3;
            uint2 pr;
            m0 = (oacc[0][0] + bflo(bp2[0].x)) * bflo(xv0.x);
            m1 = (oacc[0][1] + bfhi(bp2[0].x)) * bfhi(xv0.x);
            m2 = (oacc[0][2] + bflo(bp2[0].y)) * bflo(xv0.y);
            m3 = (oacc[0][3] + bfhi(bp2[0].y)) * bfhi(xv0.y);
            pr.x = cvt_pk_bf16(m0, m1); pr.y = cvt_pk_bf16(m2, m3);
            *(uint2*)&t_s[wv][n0*HS +  0 + kc*4] = pr;
            m0 = (oacc[1][0] + bflo(bp2[1].x)) * bflo(xv1.x);
            m1 = (oacc[1][1] + bfhi(bp2[1].x)) * bfhi(xv1.x);
            m2 = (oacc[1][2] + bflo(bp2[1].y)) * bflo(xv1.y);
            m3 = (oacc[1][3] + bfhi(bp2[1].y)) * bfhi(xv1.y);
            pr.x = cvt_pk_bf16(m0, m1); pr.y = cvt_pk_bf16(m2, m3);
            *(uint2*)&t_s[wv][n0*HS + 16 + kc*4] = pr;
            m0 = (oacc[2][0] + bflo(bp2[2].x)) * bflo(xv2.x);
            m1 = (oacc[2][1] + bfhi(bp2[2].x)) * bfhi(xv2.x);
            m2 = (oacc[2][2] + bflo(bp2[2].y)) * bflo(xv2.y);
            m3 = (oacc[2][3] + bfhi(bp2[2].y)) * bfhi(xv2.y);
            pr.x = cvt_pk_bf16(m0, m1); pr.y = cvt_pk_bf16(m2, m3);
            *(uint2*)&t_s[wv][n0*HS + 32 + kc*4] = pr;
            m0 = (oacc[3][0] + bflo(bp2[3].x)) * bflo(xv3.x);
            m1 = (oacc[3][1] + bfhi(bp2[3].x)) * bfhi(xv3.x);
            m2 = (oacc[3][2] + bflo(bp2[3].y)) * bflo(xv3.y);
            m3 = (oacc[3][3] + bfhi(bp2[3].y)) * bfhi(xv3.y);
            pr.x = cvt_pk_bf16(m0, m1); pr.y = cvt_pk_bf16(m2, m3);
            *(uint2*)&t_s[wv][n0*HS + 48 + kc*4] = pr;
        }
        wave_lds_fence();

        // segmented reduce: lane = feature; scalar flush test via fmask
        {
            float acc = 0.0f;
            #pragma unroll
            for (int r = 0; r < 16; ++r) {
                acc += bf2f(t_s[wv][r*HS + lane]);
                if ((fmask >> (tt*16 + r)) & 1ull) {     // wave-uniform branch
                    int cur = __builtin_amdgcn_readlane(cl, tt*16 + r);
                    unsafeAtomicAdd(&agg[(size_t)cur*DD + lane], acc);
                    acc = 0.0f;
                }
            }
        }
    }
}

// ---------------- MFMA out MLP (+ /cnt) + fused BN partial sums ----------------
__global__ __launch_bounds__(256, 2) void k_out_mfma(
    const float* __restrict__ agg, const u32* __restrict__ cnt,
    const float* __restrict__ x,
    const unsigned short* __restrict__ wpk,
    const float* __restrict__ b1, const float* __restrict__ b2,
    float* __restrict__ h, float* __restrict__ sums, int n)
{
    __shared__ __align__(16) unsigned short htile[4][16*PADH];
    __shared__ __align__(16) float otile[4][16*PADF];
    const int tid  = threadIdx.x;
    const int wv   = tid >> 6;
    const int lane = tid & 63;
    const int kc   = lane >> 4;
    const int n0   = lane & 15;
    const int rbase = kc * 4;

    const short8* fb = (const short8*)wpk;
    short8 bw1[4][4], bw2[2][4];
    #pragma unroll
    for (int s = 0; s < 4; ++s)
        #pragma unroll
        for (int nt = 0; nt < 4; ++nt) bw1[s][nt] = fb[(FR_O1 + s*4 + nt)*64 + lane];
    #pragma unroll
    for (int s = 0; s < 2; ++s)
        #pragma unroll
        for (int nt = 0; nt < 4; ++nt) bw2[s][nt] = fb[(FR_O2 + s*4 + nt)*64 + lane];

    float b1v[4], b2v[4];
    #pragma unroll
    for (int nt = 0; nt < 4; ++nt) { b1v[nt] = b1[nt*16 + n0]; b2v[nt] = b2[nt*16 + n0]; }

    const int base = blockIdx.x*64 + wv*16;
    int rc = min(base + n0, n - 1);
    const float* ar = agg + (size_t)rc * DD;
    const float* xr = x   + (size_t)rc * DD;
    float invc = 1.0f / fmaxf((float)cnt[rc], 1.0f);

    short8 a[4];
    #pragma unroll
    for (int m = 0; m < 4; ++m) {
        const float* src = (m < 2) ? (ar + m*32 + kc*8) : (xr + (m-2)*32 + kc*8);
        float4 u0 = *(const float4*)(src);
        float4 u1 = *(const float4*)(src + 4);
        if (m < 2) {
            u0.x*=invc; u0.y*=invc; u0.z*=invc; u0.w*=invc;
            u1.x*=invc; u1.y*=invc; u1.z*=invc; u1.w*=invc;
        }
        unsigned* au = (unsigned*)&a[m];
        au[0] = cvt_pk_bf16(u0.x, u0.y);
        au[1] = cvt_pk_bf16(u0.z, u0.w);
        au[2] = cvt_pk_bf16(u1.x, u1.y);
        au[3] = cvt_pk_bf16(u1.z, u1.w);
    }

    f32x4 zz = {0.f, 0.f, 0.f, 0.f};
    f32x4 hacc[4] = {zz, zz, zz, zz};
    #pragma unroll
    for (int m = 0; m < 4; ++m)
        #pragma unroll
        for (int nt = 0; nt < 4; ++nt)
            hacc[nt] = __builtin_amdgcn_mfma_f32_16x16x32_bf16(a[m], bw1[m][nt], hacc[nt], 0, 0, 0);

    #pragma unroll
    for (int nt = 0; nt < 4; ++nt)
        #pragma unroll
        for (int r = 0; r < 4; ++r)
            htile[wv][(rbase + r)*PADH + nt*16 + n0] = f2bf(silu(hacc[nt][r] + b1v[nt]));
    __syncthreads();

    short8 a2_0 = *(const short8*)&htile[wv][n0*PADH +  0 + kc*8];
    short8 a2_1 = *(const short8*)&htile[wv][n0*PADH + 32 + kc*8];
    f32x4 oacc[4];
    #pragma unroll
    for (int nt = 0; nt < 4; ++nt) {
        oacc[nt] = __builtin_amdgcn_mfma_f32_16x16x32_bf16(a2_0, bw2[0][nt], zz, 0, 0, 0);
        oacc[nt] = __builtin_amdgcn_mfma_f32_16x16x32_bf16(a2_1, bw2[1][nt], oacc[nt], 0, 0, 0);
    }

    #pragma unroll
    for (int nt = 0; nt < 4; ++nt)
        #pragma unroll
        for (int r = 0; r < 4; ++r)
            otile[wv][(rbase + r)*PADF + nt*16 + n0] = oacc[nt][r] + b2v[nt];
    __syncthreads();

    int ei = lane >> 2, q = lane & 3;
    int er = base + ei;
    if (er < n) {
        float4* dst = (float4*)(h + (size_t)er * DD);
        #pragma unroll
        for (int k = 0; k < 4; ++k)
            dst[q + 4*k] = *(const float4*)&otile[wv][ei*PADF + (q + 4*k)*4];
    }

    if (tid < 64) {
        int f = tid;
        float s = 0.f, qq = 0.f;
        #pragma unroll
        for (int w = 0; w < 4; ++w) {
            int base_w = blockIdx.x*64 + w*16;
            int nv = n - base_w;
            nv = nv < 0 ? 0 : (nv > 16 ? 16 : nv);
            for (int r = 0; r < nv; ++r) {
                float v = otile[w][r*PADF + f];
                s += v; qq = fmaf(v, v, qq);
            }
        }
        unsafeAtomicAdd(&sums[f], s);
        unsafeAtomicAdd(&sums[DD + f], qq);
    }
}

// ---------------- BN normalize (finalize fused in) ----------------
__global__ __launch_bounds__(256) void k_bn_norm(
    float* __restrict__ h, const float* __restrict__ sums,
    const float* __restrict__ gamma, const float* __restrict__ beta,
    float inv_n, int total4)
{
    int g = blockIdx.x*256 + threadIdx.x;
    if (g >= total4) return;
    int f0 = (g*4) & (DD-1);
    float4 v = ((const float4*)h)[g];
    float4 sm = *(const float4*)(sums + f0);
    float4 sq = *(const float4*)(sums + DD + f0);
    float4 gm = *(const float4*)(gamma + f0);
    float4 bt = *(const float4*)(beta + f0);
    float m0 = sm.x*inv_n, m1 = sm.y*inv_n, m2 = sm.z*inv_n, m3 = sm.w*inv_n;
    float s0 = gm.x * rsqrtf(sq.x*inv_n - m0*m0 + 1e-5f);
    float s1 = gm.y * rsqrtf(sq.y*inv_n - m1*m1 + 1e-5f);
    float s2 = gm.z * rsqrtf(sq.z*inv_n - m2*m2 + 1e-5f);
    float s3 = gm.w * rsqrtf(sq.w*inv_n - m3*m3 + 1e-5f);
    v.x = fmaf(v.x - m0, s0, bt.x);
    v.y = fmaf(v.y - m1, s1, bt.y);
    v.z = fmaf(v.z - m2, s2, bt.z);
    v.w = fmaf(v.w - m3, s3, bt.w);
    ((float4*)h)[g] = v;
}

static inline size_t al16(size_t v) { return (v + 15) & ~(size_t)15; }

extern "C" void kernel_launch(void* const* d_in, const int* in_sizes, int n_in,
                              void* d_out, int out_size, void* d_ws, size_t ws_size,
                              hipStream_t stream)
{
    const float* x         = (const float*)d_in[0];
    const float* pos       = (const float*)d_in[1];
    const float* edge_attr = (const float*)d_in[2];
    const int*   row       = (const int*)d_in[3];
    const int*   col       = (const int*)d_in[4];
    const float* nW1 = (const float*)d_in[5];
    const float* nb1 = (const float*)d_in[6];
    const float* nW2 = (const float*)d_in[7];
    const float* nb2 = (const float*)d_in[8];
    const float* eW1 = (const float*)d_in[9];
    const float* eb1 = (const float*)d_in[10];
    const float* eW2 = (const float*)d_in[11];
    const float* eb2 = (const float*)d_in[12];
    const float* oW1 = (const float*)d_in[13];
    const float* ob1 = (const float*)d_in[14];
    const float* oW2 = (const float*)d_in[15];
    const float* ob2 = (const float*)d_in[16];
    const float* gamma = (const float*)d_in[17];
    const float* beta  = (const float*)d_in[18];

    const int N = in_sizes[0] / DD;   // 100000  (< 2^17 for packing)
    const int E = in_sizes[3];        // 1600000 (< 2^21 for packing)
    const int NB = (N + 255) / 256;   // 391
    const int nodeBlocks = (N + 63) / 64;       // 1563
    const int histBlocks = (E/4 + 255) / 256;   // 1563

    float* hout = (float*)d_out;
    char* ws = (char*)d_ws;

    size_t o_xtb  = 0;
    size_t o_cnt  = o_xtb  + (size_t)N*DD*2;
    size_t o_sums = o_cnt  + (size_t)N*4;
    size_t o_gctr = o_sums + 128*4;
    size_t o_agg  = o_gctr + 16;                // 16B pad keeps alignment
    size_t o_wp   = o_agg  + (size_t)N*DD*4;
    size_t o_wpk  = al16(o_wp + (size_t)N*4);
    size_t o_ce   = al16(o_wpk + (size_t)FR_TOT*64*8*2);
    size_t need   = o_ce + (size_t)E*8;

    if (ws_size < need) return;

    unsigned short* x_tb = (unsigned short*)(ws + o_xtb);
    u32*   cnt  = (u32*)(ws + o_cnt);
    float* sums = (float*)(ws + o_sums);
    u32*   gctr = (u32*)(ws + o_gctr);
    float* agg  = (float*)(ws + o_agg);
    u32*   wp   = (u32*)(ws + o_wp);
    unsigned short* wpk = (unsigned short*)(ws + o_wpk);
    u64*   ce   = (u64*)(ws + o_ce);

    // zero region: cnt (N u32) + sums (128) + gctr pad (4 u32) = N+132 u32
    const int nz4 = (N + 132 + 3) / 4;
    const int zBlocks = (nz4 + 255) / 256;

    k_pack_zero<<<1 + zBlocks, 256, 0, stream>>>(eW1, eW2, nW1, nW2, oW1, oW2, wpk,
                                                 (uint4*)cnt, nz4);
    k_node_hist<<<nodeBlocks + histBlocks, 256, 0, stream>>>(
        x, wpk, nb1, nb2, x_tb, N, nodeBlocks, col, cnt, E);
    k_scan_bump<<<NB, 256, 0, stream>>>(cnt, wp, gctr, N);
    k_scatter<<<(E + 255)/256, 256, 0, stream>>>(row, col, wp, ce, agg, N*DD/4, E);
    k_edge_fused<<<(E + 255)/256, 256, 0, stream>>>(pos, edge_attr, ce, x_tb,
                                                    wpk, eb1, eb2, agg, E);
    k_out_mfma<<<(N + 63)/64, 256, 0, stream>>>(agg, cnt, x, wpk, ob1, ob2, hout, sums, N);
    k_bn_norm<<<(N*DD/4 + 255)/256, 256, 0, stream>>>(hout, sums, gamma, beta,
                                                      1.0f/(float)N, N*DD/4);
}